// Round 6
// baseline (81013.666 us; speedup 1.0000x reference)
//
#include <hip/hip_runtime.h>
#include <math.h>

#define NROWS 4096
#define DZ    128
#define DH    512
#define VOC   64
#define DE    128
#define MAXLEN 128
#define PAD_T 0
#define SOS_T 1
#define EOS_T 2

// ---------------- transpose: in [R][C] -> out [C][R] ----------------
__global__ void transpose_k(const float* __restrict__ in, float* __restrict__ out,
                            int R, int C) {
  __shared__ float tile[32][33];
  int cb = blockIdx.x * 32, rb = blockIdx.y * 32;
  int tx = threadIdx.x, ty = threadIdx.y;  // blockDim (32,8)
  #pragma unroll
  for (int i = ty; i < 32; i += 8)
    tile[i][tx] = in[(size_t)(rb + i) * C + (cb + tx)];
  __syncthreads();
  #pragma unroll
  for (int i = ty; i < 32; i += 8)
    out[(size_t)(cb + i) * R + (rb + tx)] = tile[tx][i];
}

// ---------------- repack: in [Rn][K] -> plane P[((k>>2)*Rn + r)*4 + (k&3)] ----
__global__ void repack_k(const float* __restrict__ in, float* __restrict__ out,
                         int Rn, int K) {
  int k = blockIdx.y * 128 + threadIdx.x;
  int r = blockIdx.x;
  out[((size_t)(k >> 2) * Rn + r) * 4 + (k & 3)] = in[(size_t)r * K + k];
}

// ---------------- G0[v] = emb[v] @ W_ih0^T + b_ih0  (uses packed Wi0) --------
__global__ __launch_bounds__(64) void build_g0(
    const float* __restrict__ emb, const float* __restrict__ P,
    const float* __restrict__ bi, float* __restrict__ G0) {
  int lane = threadIdx.x;
  int j = blockIdx.x * 64 + lane;   // grid.x = DH/64
  int v = blockIdx.y;               // grid.y = VOC
  const size_t KDH = (size_t)DE * DH;
  const float4* e4 = (const float4*)(emb + (size_t)v * DE);
  float ar = bi[j], az = bi[DH + j], an = bi[2 * DH + j];
  for (int k4 = 0; k4 < DE / 4; ++k4) {
    size_t off = ((size_t)k4 * DH + j);
    float4 wr = ((const float4*)P)[off];
    float4 wz = ((const float4*)(P + KDH))[off];
    float4 wn = ((const float4*)(P + 2 * KDH))[off];
    float4 x = e4[k4];
    ar = fmaf(x.x, wr.x, ar); ar = fmaf(x.y, wr.y, ar);
    ar = fmaf(x.z, wr.z, ar); ar = fmaf(x.w, wr.w, ar);
    az = fmaf(x.x, wz.x, az); az = fmaf(x.y, wz.y, az);
    az = fmaf(x.z, wz.z, az); az = fmaf(x.w, wz.w, az);
    an = fmaf(x.x, wn.x, an); an = fmaf(x.y, wn.y, an);
    an = fmaf(x.z, wn.z, an); an = fmaf(x.w, wn.w, an);
  }
  G0[(size_t)v * 3 * DH + j] = ar;
  G0[(size_t)v * 3 * DH + DH + j] = az;
  G0[(size_t)v * 3 * DH + 2 * DH + j] = an;
}

// ---------------- init: h0 = Z @ z2h_w^T + b; state init ----------------
__global__ __launch_bounds__(256) void init_kernel(
    const float* __restrict__ Z, const float* __restrict__ z2hT,
    const float* __restrict__ z2h_b,
    float* __restrict__ h1, float* __restrict__ h2, float* __restrict__ h3,
    int* __restrict__ tok, int* __restrict__ eos, int* __restrict__ outi) {
  int lane = threadIdx.x & 63;
  int wave = __builtin_amdgcn_readfirstlane((int)(threadIdx.x >> 6));
  int r = blockIdx.x * 4 + wave;          // grid.x = NROWS/4
  int j = blockIdx.y * 64 + lane;         // grid.y = DH/64
  float acc = z2h_b[j];
  const float* zr = Z + (size_t)r * DZ;   // wave-uniform -> s_load
  #pragma unroll 4
  for (int k = 0; k < DZ; ++k)
    acc = fmaf(zr[k], z2hT[(size_t)k * DH + j], acc);
  size_t o = (size_t)r * DH + j;
  h1[o] = acc; h2[o] = acc; h3[o] = acc;
  if (blockIdx.y == 0 && lane == 0) {
    tok[r] = SOS_T;
    eos[r] = 0;
    outi[(size_t)r * MAXLEN] = SOS_T;               // X_gen[:,0] = SOS
    outi[(size_t)NROWS * MAXLEN + r] = MAXLEN;      // seq_lens init
  }
}

// ---------------- fused GRU cell layer ----------------
// Round-2 mapping, R=16: lane -> gate unit j (64/wave), wave -> 16 contiguous
// rows (single SGPR base + immediate offsets for activation s_loads).
// 1D grid, j-tile = blockIdx.x & 7 -> XCD-aligned L2 reuse of weight slice.
// Weights packed per gate plane [K/4][DH][4]; explicit next-k4 reg prefetch.
template <bool IS_L0>
__global__ __launch_bounds__(256, 2) void gru_kernel(
    const float* __restrict__ Xin,    // [NROWS][DH]   (L1/L2 only)
    const int* __restrict__ tok,      // [NROWS]       (L0 only)
    const float* __restrict__ G0,     // [VOC][3*DH]   (L0 only)
    const float* __restrict__ Hprev,  // [NROWS][DH]
    const float* __restrict__ WiP,    // packed input weights (L1/L2 only)
    const float* __restrict__ WhP,    // packed hidden weights
    const float* __restrict__ bi, const float* __restrict__ bh,
    float* __restrict__ Hnew) {
  constexpr int R = 16;
  const size_t KDH = (size_t)DH * DH;   // per-gate plane size (K=DH)
  int lane = threadIdx.x & 63;
  int wave = __builtin_amdgcn_readfirstlane((int)(threadIdx.x >> 6));
  int jt = blockIdx.x & 7;               // j-tile -> XCD id (L2 locality)
  int rb = blockIdx.x >> 3;              // row block; grid.x = (NROWS/64)*8
  int r0 = rb * 64 + wave * R;
  int j  = jt * 64 + lane;

  float accr[R], accz[R], accin[R], acchn[R];
  float bhr = bh[j], bhz = bh[DH + j], bhn = bh[2 * DH + j];
  if constexpr (IS_L0) {
    #pragma unroll
    for (int r = 0; r < R; ++r) {
      const float* g = G0 + (size_t)tok[r0 + r] * (3 * DH);
      accr[r]  = g[j] + bhr;
      accz[r]  = g[DH + j] + bhz;
      accin[r] = g[2 * DH + j];
      acchn[r] = bhn;
    }
  } else {
    float bir = bi[j], biz = bi[DH + j], bin = bi[2 * DH + j];
    #pragma unroll
    for (int r = 0; r < R; ++r) {
      accr[r] = bir + bhr; accz[r] = biz + bhz; accin[r] = bin; acchn[r] = bhn;
    }
    // phase 1: gi += x @ Wi^T
    const float4* xb = (const float4*)(Xin + (size_t)r0 * DH);  // single uniform base
    const float4* Wr = (const float4*)WiP;
    const float4* Wz = (const float4*)(WiP + KDH);
    const float4* Wn = (const float4*)(WiP + 2 * KDH);
    float4 wr = Wr[j], wz = Wz[j], wn = Wn[j];
    for (int k4 = 0; k4 < DH / 4; ++k4) {
      int k4n = (k4 + 1 < DH / 4) ? k4 + 1 : k4;   // prefetch next (last reloads)
      size_t offn = (size_t)k4n * DH + j;
      float4 nwr = Wr[offn], nwz = Wz[offn], nwn = Wn[offn];
      #pragma unroll
      for (int r = 0; r < R; ++r) {
        float4 x = xb[r * (DH / 4) + k4];   // s_load_dwordx4, base+imm
        accr[r]  = fmaf(x.x, wr.x, accr[r]);  accr[r]  = fmaf(x.y, wr.y, accr[r]);
        accr[r]  = fmaf(x.z, wr.z, accr[r]);  accr[r]  = fmaf(x.w, wr.w, accr[r]);
        accz[r]  = fmaf(x.x, wz.x, accz[r]);  accz[r]  = fmaf(x.y, wz.y, accz[r]);
        accz[r]  = fmaf(x.z, wz.z, accz[r]);  accz[r]  = fmaf(x.w, wz.w, accz[r]);
        accin[r] = fmaf(x.x, wn.x, accin[r]); accin[r] = fmaf(x.y, wn.y, accin[r]);
        accin[r] = fmaf(x.z, wn.z, accin[r]); accin[r] = fmaf(x.w, wn.w, accin[r]);
      }
      wr = nwr; wz = nwz; wn = nwn;
    }
  }
  // phase 2: gh += h @ Wh^T
  {
    const float4* hb = (const float4*)(Hprev + (size_t)r0 * DH);  // uniform base
    const float4* Wr = (const float4*)WhP;
    const float4* Wz = (const float4*)(WhP + KDH);
    const float4* Wn = (const float4*)(WhP + 2 * KDH);
    float4 wr = Wr[j], wz = Wz[j], wn = Wn[j];
    for (int k4 = 0; k4 < DH / 4; ++k4) {
      int k4n = (k4 + 1 < DH / 4) ? k4 + 1 : k4;
      size_t offn = (size_t)k4n * DH + j;
      float4 nwr = Wr[offn], nwz = Wz[offn], nwn = Wn[offn];
      #pragma unroll
      for (int r = 0; r < R; ++r) {
        float4 h = hb[r * (DH / 4) + k4];   // s_load_dwordx4, base+imm
        accr[r]  = fmaf(h.x, wr.x, accr[r]);  accr[r]  = fmaf(h.y, wr.y, accr[r]);
        accr[r]  = fmaf(h.z, wr.z, accr[r]);  accr[r]  = fmaf(h.w, wr.w, accr[r]);
        accz[r]  = fmaf(h.x, wz.x, accz[r]);  accz[r]  = fmaf(h.y, wz.y, accz[r]);
        accz[r]  = fmaf(h.z, wz.z, accz[r]);  accz[r]  = fmaf(h.w, wz.w, accz[r]);
        acchn[r] = fmaf(h.x, wn.x, acchn[r]); acchn[r] = fmaf(h.y, wn.y, acchn[r]);
        acchn[r] = fmaf(h.z, wn.z, acchn[r]); acchn[r] = fmaf(h.w, wn.w, acchn[r]);
      }
      wr = nwr; wz = nwz; wn = nwn;
    }
  }
  // gates + blend
  #pragma unroll
  for (int r = 0; r < R; ++r) {
    float rg = 1.f / (1.f + expf(-accr[r]));
    float zg = 1.f / (1.f + expf(-accz[r]));
    float nn = tanhf(accin[r] + rg * acchn[r]);
    size_t o = (size_t)(r0 + r) * DH + j;
    float hp = Hprev[o];
    Hnew[o] = (1.f - zg) * nn + zg * hp;
  }
}

// ---------------- logits + argmax + EOS bookkeeping ----------------
// wave -> 4 rows, lane = vocab id; h2v packed [k/4][VOC][4]
__global__ __launch_bounds__(256) void argmax_kernel(
    const float* __restrict__ H3, const float* __restrict__ h2vP,
    const float* __restrict__ h2v_b,
    int* __restrict__ tok, int* __restrict__ eos,
    int* __restrict__ outi, int t) {
  int lane = threadIdx.x & 63;
  int wave = __builtin_amdgcn_readfirstlane((int)(threadIdx.x >> 6));
  int r0 = blockIdx.x * 16 + wave * 4;    // grid.x = NROWS/16
  float acc[4];
  float b = h2v_b[lane];
  #pragma unroll
  for (int i = 0; i < 4; ++i) acc[i] = b;
  const float4* w4 = (const float4*)h2vP;
  const float4* h4 = (const float4*)(H3 + (size_t)r0 * DH);  // uniform base
  #pragma unroll 2
  for (int k4 = 0; k4 < DH / 4; ++k4) {
    float4 w = w4[(size_t)k4 * VOC + lane];       // coalesced vector
    #pragma unroll
    for (int i = 0; i < 4; ++i) {
      float4 h = h4[i * (DH / 4) + k4];            // s_load, base+imm
      acc[i] = fmaf(h.x, w.x, acc[i]); acc[i] = fmaf(h.y, w.y, acc[i]);
      acc[i] = fmaf(h.z, w.z, acc[i]); acc[i] = fmaf(h.w, w.w, acc[i]);
    }
  }
  #pragma unroll
  for (int i = 0; i < 4; ++i) {
    // argmax across 64 lanes; tie -> lowest index (jnp.argmax = first max)
    float v = acc[i]; int idx = lane;
    #pragma unroll
    for (int off = 32; off >= 1; off >>= 1) {
      float v2 = __shfl_xor(v, off);
      int   i2 = __shfl_xor(idx, off);
      if (v2 > v || (v2 == v && i2 < idx)) { v = v2; idx = i2; }
    }
    if (lane == 0) {
      int r = r0 + i;
      int e = eos[r];
      int x_next = idx;
      outi[(size_t)r * MAXLEN + t] = e ? PAD_T : x_next;
      if (!e && x_next == EOS_T) {
        outi[(size_t)NROWS * MAXLEN + r] = t + 1;  // seq_lens
        eos[r] = 1;
      }
      tok[r] = x_next;  // raw x_next feeds back
    }
  }
}

// ---------------- host-side orchestration ----------------
extern "C" void kernel_launch(void* const* d_in, const int* in_sizes, int n_in,
                              void* d_out, int out_size, void* d_ws, size_t ws_size,
                              hipStream_t stream) {
  const float* Z      = (const float*)d_in[0];
  const float* emb    = (const float*)d_in[1];
  const float* z2h_w  = (const float*)d_in[2];
  const float* z2h_b  = (const float*)d_in[3];
  const float* W_ih0  = (const float*)d_in[4];
  const float* W_hh0  = (const float*)d_in[5];
  const float* b_ih0  = (const float*)d_in[6];
  const float* b_hh0  = (const float*)d_in[7];
  const float* W_ih1  = (const float*)d_in[8];
  const float* W_hh1  = (const float*)d_in[9];
  const float* b_ih1  = (const float*)d_in[10];
  const float* b_hh1  = (const float*)d_in[11];
  const float* W_ih2  = (const float*)d_in[12];
  const float* W_hh2  = (const float*)d_in[13];
  const float* b_ih2  = (const float*)d_in[14];
  const float* b_hh2  = (const float*)d_in[15];
  const float* h2v_w  = (const float*)d_in[16];
  const float* h2v_b  = (const float*)d_in[17];
  int* outi = (int*)d_out;

  // workspace layout (all chunks 16B-aligned)
  float* p = (float*)d_ws;
  float* WiP0 = p; p += (size_t)3 * DE * DH;
  float* WhP0 = p; p += (size_t)3 * DH * DH;
  float* WiP1 = p; p += (size_t)3 * DH * DH;
  float* WhP1 = p; p += (size_t)3 * DH * DH;
  float* WiP2 = p; p += (size_t)3 * DH * DH;
  float* WhP2 = p; p += (size_t)3 * DH * DH;
  float* G0   = p; p += (size_t)VOC * 3 * DH;
  float* z2hT = p; p += (size_t)DZ * DH;
  float* h2vP = p; p += (size_t)DH * VOC;
  float* h1a = p; p += (size_t)NROWS * DH;
  float* h1b = p; p += (size_t)NROWS * DH;
  float* h2a = p; p += (size_t)NROWS * DH;
  float* h2b = p; p += (size_t)NROWS * DH;
  float* h3a = p; p += (size_t)NROWS * DH;
  float* h3b = p; p += (size_t)NROWS * DH;
  int* tokb = (int*)p;
  int* eosb = tokb + NROWS;

  // one-time: repack weights per gate plane
  struct WEnt { const float* src; float* dst; int K; };
  WEnt wl[6] = {
    {W_ih0, WiP0, DE}, {W_hh0, WhP0, DH}, {W_ih1, WiP1, DH},
    {W_hh1, WhP1, DH}, {W_ih2, WiP2, DH}, {W_hh2, WhP2, DH}};
  for (int m = 0; m < 6; ++m)
    for (int g = 0; g < 3; ++g)
      repack_k<<<dim3(DH, wl[m].K / 128), 128, 0, stream>>>(
          wl[m].src + (size_t)g * DH * wl[m].K,
          wl[m].dst + (size_t)g * wl[m].K * DH, DH, wl[m].K);
  repack_k<<<dim3(VOC, DH / 128), 128, 0, stream>>>(h2v_w, h2vP, VOC, DH);
  transpose_k<<<dim3(DZ / 32, DH / 32), dim3(32, 8), 0, stream>>>(z2h_w, z2hT, DH, DZ);
  build_g0<<<dim3(DH / 64, VOC), 64, 0, stream>>>(emb, WiP0, b_ih0, G0);

  init_kernel<<<dim3(NROWS / 4, DH / 64), 256, 0, stream>>>(
      Z, z2hT, z2h_b, h1a, h2a, h3a, tokb, eosb, outi);

  const int ngrid = (NROWS / 64) * 8;   // 512 blocks, j-tile = blockIdx & 7
  float* h1p = h1a; float* h1n = h1b;
  float* h2p = h2a; float* h2n = h2b;
  float* h3p = h3a; float* h3n = h3b;
  for (int t = 1; t < MAXLEN; ++t) {
    gru_kernel<true><<<ngrid, 256, 0, stream>>>(
        nullptr, tokb, G0, h1p, nullptr, WhP0, nullptr, b_hh0, h1n);
    gru_kernel<false><<<ngrid, 256, 0, stream>>>(
        h1n, nullptr, nullptr, h2p, WiP1, WhP1, b_ih1, b_hh1, h2n);
    gru_kernel<false><<<ngrid, 256, 0, stream>>>(
        h2n, nullptr, nullptr, h3p, WiP2, WhP2, b_ih2, b_hh2, h3n);
    argmax_kernel<<<dim3(NROWS / 16), 256, 0, stream>>>(
        h3n, h2vP, h2v_b, tokb, eosb, outi, t);
    float* tmp;
    tmp = h1p; h1p = h1n; h1n = tmp;
    tmp = h2p; h2p = h2n; h2n = tmp;
    tmp = h3p; h3p = h3n; h3n = tmp;
  }
}

// Round 7
// 44421.875 us; speedup vs baseline: 1.8237x; 1.8237x over previous
//
#include <hip/hip_runtime.h>
#include <math.h>

#define NROWS 4096
#define DZ    128
#define DH    512
#define VOC   64
#define DE    128
#define MAXLEN 128
#define PAD_T 0
#define SOS_T 1
#define EOS_T 2

typedef __attribute__((ext_vector_type(8))) short bf16x8;   // 8 bf16 (4 VGPRs)
typedef __attribute__((ext_vector_type(4))) float f32x4;

__device__ __forceinline__ unsigned short f2bf(float x) {   // RN-even fp32->bf16
  unsigned u = __float_as_uint(x);
  unsigned r = (u + 0x7FFFu + ((u >> 16) & 1u)) >> 16;
  return (unsigned short)r;
}
__device__ __forceinline__ float bf2f(unsigned short b) {
  return __uint_as_float(((unsigned)b) << 16);
}
__device__ __forceinline__ f32x4 mfma_bf16(bf16x8 a, bf16x8 b, f32x4 c) {
  return __builtin_amdgcn_mfma_f32_16x16x32_bf16(a, b, c, 0, 0, 0);
}

// ---------------- transpose: in [R][C] -> out [C][R] ----------------
__global__ void transpose_k(const float* __restrict__ in, float* __restrict__ out,
                            int R, int C) {
  __shared__ float tile[32][33];
  int cb = blockIdx.x * 32, rb = blockIdx.y * 32;
  int tx = threadIdx.x, ty = threadIdx.y;  // blockDim (32,8)
  #pragma unroll
  for (int i = ty; i < 32; i += 8)
    tile[i][tx] = in[(size_t)(rb + i) * C + (cb + tx)];
  __syncthreads();
  #pragma unroll
  for (int i = ty; i < 32; i += 8)
    out[(size_t)(cb + i) * R + (rb + tx)] = tile[tx][i];
}

// ---------------- repack h2v: in [Rn][K] -> P[((k>>2)*Rn + r)*4 + (k&3)] -----
__global__ void repack_k(const float* __restrict__ in, float* __restrict__ out,
                         int Rn, int K) {
  int k = blockIdx.y * 128 + threadIdx.x;
  int r = blockIdx.x;
  out[((size_t)(k >> 2) * Rn + r) * 4 + (k & 3)] = in[(size_t)r * K + k];
}

// ---- pack weights to 3-limb bf16 B-fragments -------------------------------
// W [3*DH][512] fp32 -> out[g][l][nt][kc][lane][j] bf16
// value = limb_l( W[g*DH + nt*16 + (lane&15)][kc*32 + (lane>>4)*8 + j] )
__global__ void pack_w3(const float* __restrict__ W, unsigned short* __restrict__ out) {
  size_t i = (size_t)blockIdx.x * 256 + threadIdx.x;  // total 9*32*16*512
  int j = (int)(i & 7);
  int lane = (int)((i >> 3) & 63);
  size_t t = i >> 9;
  int kc = (int)(t & 15); t >>= 4;
  int nt = (int)(t & 31); t >>= 5;
  int l = (int)(t % 3);
  int g = (int)(t / 3);
  int n = nt * 16 + (lane & 15);
  int k = kc * 32 + (lane >> 4) * 8 + j;
  float w = W[(size_t)(g * DH + n) * DH + k];
  unsigned short wh = f2bf(w); float fh = bf2f(wh);
  unsigned short wm = f2bf(w - fh); float fm = bf2f(wm);
  unsigned short wl = f2bf(w - fh - fm);
  out[i] = (l == 0) ? wh : (l == 1) ? wm : wl;
}

// ---------------- G0[v][jj] = sum_k emb[v][k] * WiT0[k][jj] + bi[jj] ---------
__global__ __launch_bounds__(256) void build_g0(
    const float* __restrict__ emb, const float* __restrict__ WiT0,
    const float* __restrict__ bi, float* __restrict__ G0) {
  int jj = blockIdx.y * 256 + threadIdx.x;   // grid.y = 3*DH/256
  int v = blockIdx.x;                        // grid.x = VOC
  float acc = bi[jj];
  const float* e = emb + (size_t)v * DE;     // wave-uniform -> s_load
  #pragma unroll 4
  for (int k = 0; k < DE; ++k)
    acc = fmaf(e[k], WiT0[(size_t)k * (3 * DH) + jj], acc);
  G0[(size_t)v * (3 * DH) + jj] = acc;
}

// ---------------- init: h0 = Z @ z2h_w^T + b; 3-limb state init --------------
__global__ __launch_bounds__(256) void init_kernel(
    const float* __restrict__ Z, const float* __restrict__ z2hT,
    const float* __restrict__ z2h_b,
    unsigned short* __restrict__ h1H, unsigned short* __restrict__ h1M, unsigned short* __restrict__ h1L,
    unsigned short* __restrict__ h2H, unsigned short* __restrict__ h2M, unsigned short* __restrict__ h2L,
    unsigned short* __restrict__ h3H, unsigned short* __restrict__ h3M, unsigned short* __restrict__ h3L,
    int* __restrict__ tok, int* __restrict__ eos, int* __restrict__ outi) {
  int lane = threadIdx.x & 63;
  int wave = __builtin_amdgcn_readfirstlane((int)(threadIdx.x >> 6));
  int r = blockIdx.x * 4 + wave;          // grid.x = NROWS/4
  int j = blockIdx.y * 64 + lane;         // grid.y = DH/64
  float acc = z2h_b[j];
  const float* zr = Z + (size_t)r * DZ;   // wave-uniform -> s_load
  #pragma unroll 4
  for (int k = 0; k < DZ; ++k)
    acc = fmaf(zr[k], z2hT[(size_t)k * DH + j], acc);
  size_t o = (size_t)r * DH + j;
  unsigned short uh = f2bf(acc); float fh = bf2f(uh);
  unsigned short um = f2bf(acc - fh); float fm = bf2f(um);
  unsigned short ul = f2bf(acc - fh - fm);
  h1H[o] = uh; h1M[o] = um; h1L[o] = ul;
  h2H[o] = uh; h2M[o] = um; h2L[o] = ul;
  h3H[o] = uh; h3M[o] = um; h3L[o] = ul;
  if (blockIdx.y == 0 && lane == 0) {
    tok[r] = SOS_T;
    eos[r] = 0;
    outi[(size_t)r * MAXLEN] = SOS_T;               // X_gen[:,0] = SOS
    outi[(size_t)NROWS * MAXLEN + r] = MAXLEN;      // seq_lens init
  }
}

// ---- one GEMM phase: acc += A(3-limb) x W(3-limb), 6 products --------------
// planes: 0=r, 1=z, (2 or 3)=n depending on phase
__device__ __forceinline__ void gemm_phase(
    const unsigned short* __restrict__ AH, const unsigned short* __restrict__ AM,
    const unsigned short* __restrict__ AL, const unsigned short* __restrict__ Wp,
    int arow0, int col, int quad, int lane, int ntile, int nplane,
    f32x4 acc[2][4]) {
  const int kb = quad * 8;
  const size_t LSTR = (size_t)32 * 16 * 512;   // limb stride in pack
  for (int kc = 0; kc < 16; ++kc) {
    bf16x8 a[2][3];
    #pragma unroll
    for (int mt = 0; mt < 2; ++mt) {
      size_t ao = (size_t)(arow0 + mt * 16 + col) * DH + kc * 32 + kb;
      a[mt][0] = *(const bf16x8*)(AH + ao);
      a[mt][1] = *(const bf16x8*)(AM + ao);
      a[mt][2] = *(const bf16x8*)(AL + ao);
    }
    #pragma unroll
    for (int g = 0; g < 3; ++g) {
      size_t bo = ((((size_t)g * 3) * 32 + ntile) * 16 + kc) * 512 + (size_t)lane * 8;
      bf16x8 b0 = *(const bf16x8*)(Wp + bo);             // limb h
      bf16x8 b1 = *(const bf16x8*)(Wp + bo + LSTR);      // limb m
      bf16x8 b2 = *(const bf16x8*)(Wp + bo + 2 * LSTR);  // limb l
      int pl = (g == 2) ? nplane : g;
      #pragma unroll
      for (int mt = 0; mt < 2; ++mt) {
        f32x4 c = acc[mt][pl];
        c = mfma_bf16(a[mt][2], b0, c);   // Al*Wh  (~2^-18)
        c = mfma_bf16(a[mt][0], b2, c);   // Ah*Wl
        c = mfma_bf16(a[mt][1], b1, c);   // Am*Wm
        c = mfma_bf16(a[mt][1], b0, c);   // Am*Wh  (~2^-9)
        c = mfma_bf16(a[mt][0], b1, c);   // Ah*Wm
        c = mfma_bf16(a[mt][0], b0, c);   // Ah*Wh
        acc[mt][pl] = c;
      }
    }
  }
}

// ---------------- fused GRU layer via MFMA ----------------
// wg = 4 waves; wave tile = 32 rows x (16 j x 3 gates). grid = 32*32 = 1024.
template <bool IS_L0>
__global__ __launch_bounds__(256, 3) void gru_mfma(
    const unsigned short* __restrict__ XH, const unsigned short* __restrict__ XM,
    const unsigned short* __restrict__ XL,   // phase-1 A limbs (L1/L2)
    const unsigned short* __restrict__ HH, const unsigned short* __restrict__ HM,
    const unsigned short* __restrict__ HL,   // phase-2 A limbs (h_prev)
    const unsigned short* __restrict__ WiPk, const unsigned short* __restrict__ WhPk,
    const int* __restrict__ tok, const float* __restrict__ G0,
    const float* __restrict__ bi, const float* __restrict__ bh,
    unsigned short* __restrict__ OH, unsigned short* __restrict__ OM,
    unsigned short* __restrict__ OL, float* __restrict__ Hf32) {
  const int lane = threadIdx.x & 63;
  const int wave = __builtin_amdgcn_readfirstlane((int)(threadIdx.x >> 6));
  const int wg = blockIdx.x;
  const int ntile = wg & 31;           // j-tile
  const int rblk = wg >> 5;            // row block
  const int m0 = rblk * 128 + wave * 32;
  const int col = lane & 15, quad = lane >> 4;
  const int jc = ntile * 16 + col;

  f32x4 acc[2][4];                     // [mt][plane: r,z,in,hn]
  #pragma unroll
  for (int mt = 0; mt < 2; ++mt)
    #pragma unroll
    for (int p = 0; p < 4; ++p)
      acc[mt][p] = (f32x4){0.f, 0.f, 0.f, 0.f};

  if constexpr (!IS_L0)
    gemm_phase(XH, XM, XL, WiPk, m0, col, quad, lane, ntile, 2, acc);
  gemm_phase(HH, HM, HL, WhPk, m0, col, quad, lane, ntile, 3, acc);

  float bhr = bh[jc], bhz = bh[DH + jc], bhn = bh[2 * DH + jc];
  float bir = 0.f, biz = 0.f, bin = 0.f;
  if constexpr (!IS_L0) { bir = bi[jc]; biz = bi[DH + jc]; bin = bi[2 * DH + jc]; }

  #pragma unroll
  for (int mt = 0; mt < 2; ++mt) {
    #pragma unroll
    for (int i = 0; i < 4; ++i) {
      int row = m0 + mt * 16 + quad * 4 + i;
      float gr = acc[mt][0][i] + bhr;
      float gz = acc[mt][1][i] + bhz;
      float gin = acc[mt][2][i];
      float ghn = acc[mt][3][i] + bhn;
      if constexpr (IS_L0) {
        const float* g0p = G0 + (size_t)tok[row] * (3 * DH);
        gr += g0p[jc]; gz += g0p[DH + jc]; gin += g0p[2 * DH + jc];
      } else {
        gr += bir; gz += biz; gin += bin;
      }
      float rg = 1.f / (1.f + expf(-gr));
      float zg = 1.f / (1.f + expf(-gz));
      float nn = tanhf(gin + rg * ghn);
      size_t ho = (size_t)row * DH + jc;
      float hp = bf2f(HH[ho]) + bf2f(HM[ho]) + bf2f(HL[ho]);
      float hv = (1.f - zg) * nn + zg * hp;
      unsigned short uh = f2bf(hv); float fh = bf2f(uh);
      unsigned short um = f2bf(hv - fh); float fm = bf2f(um);
      unsigned short ul = f2bf(hv - fh - fm);
      OH[ho] = uh; OM[ho] = um; OL[ho] = ul;
      if (Hf32) Hf32[ho] = hv;
    }
  }
}

// ---------------- logits + argmax + EOS bookkeeping ----------------
__global__ __launch_bounds__(256) void argmax_kernel(
    const float* __restrict__ H3, const float* __restrict__ h2vP,
    const float* __restrict__ h2v_b,
    int* __restrict__ tok, int* __restrict__ eos,
    int* __restrict__ outi, int t) {
  int lane = threadIdx.x & 63;
  int wave = __builtin_amdgcn_readfirstlane((int)(threadIdx.x >> 6));
  int r0 = blockIdx.x * 16 + wave * 4;    // grid.x = NROWS/16
  float acc[4];
  float b = h2v_b[lane];
  #pragma unroll
  for (int i = 0; i < 4; ++i) acc[i] = b;
  const float4* w4 = (const float4*)h2vP;
  const float4* h4[4];
  #pragma unroll
  for (int i = 0; i < 4; ++i)
    h4[i] = (const float4*)(H3 + (size_t)(r0 + i) * DH);
  #pragma unroll 2
  for (int k4 = 0; k4 < DH / 4; ++k4) {
    float4 w = w4[(size_t)k4 * VOC + lane];       // coalesced vector
    #pragma unroll
    for (int i = 0; i < 4; ++i) {
      float4 h = h4[i][k4];                        // wave-uniform -> s_load
      acc[i] = fmaf(h.x, w.x, acc[i]); acc[i] = fmaf(h.y, w.y, acc[i]);
      acc[i] = fmaf(h.z, w.z, acc[i]); acc[i] = fmaf(h.w, w.w, acc[i]);
    }
  }
  #pragma unroll
  for (int i = 0; i < 4; ++i) {
    float v = acc[i]; int idx = lane;
    #pragma unroll
    for (int off = 32; off >= 1; off >>= 1) {
      float v2 = __shfl_xor(v, off);
      int   i2 = __shfl_xor(idx, off);
      if (v2 > v || (v2 == v && i2 < idx)) { v = v2; idx = i2; }
    }
    if (lane == 0) {
      int r = r0 + i;
      int e = eos[r];
      int x_next = idx;
      outi[(size_t)r * MAXLEN + t] = e ? PAD_T : x_next;
      if (!e && x_next == EOS_T) {
        outi[(size_t)NROWS * MAXLEN + r] = t + 1;  // seq_lens
        eos[r] = 1;
      }
      tok[r] = x_next;
    }
  }
}

// ---------------- host-side orchestration ----------------
extern "C" void kernel_launch(void* const* d_in, const int* in_sizes, int n_in,
                              void* d_out, int out_size, void* d_ws, size_t ws_size,
                              hipStream_t stream) {
  const float* Z      = (const float*)d_in[0];
  const float* emb    = (const float*)d_in[1];
  const float* z2h_w  = (const float*)d_in[2];
  const float* z2h_b  = (const float*)d_in[3];
  const float* W_ih0  = (const float*)d_in[4];
  const float* W_hh0  = (const float*)d_in[5];
  const float* b_ih0  = (const float*)d_in[6];
  const float* b_hh0  = (const float*)d_in[7];
  const float* W_ih1  = (const float*)d_in[8];
  const float* W_hh1  = (const float*)d_in[9];
  const float* b_ih1  = (const float*)d_in[10];
  const float* b_hh1  = (const float*)d_in[11];
  const float* W_ih2  = (const float*)d_in[12];
  const float* W_hh2  = (const float*)d_in[13];
  const float* b_ih2  = (const float*)d_in[14];
  const float* b_hh2  = (const float*)d_in[15];
  const float* h2v_w  = (const float*)d_in[16];
  const float* h2v_b  = (const float*)d_in[17];
  int* outi = (int*)d_out;

  const size_t PKS = (size_t)9 * 32 * 16 * 512;   // 2,359,296 ushorts per matrix
  const size_t PLN = (size_t)NROWS * DH;          // 2,097,152 ushorts per plane

  unsigned short* us = (unsigned short*)d_ws;
  unsigned short* Wh0P = us; us += PKS;
  unsigned short* Wi1P = us; us += PKS;
  unsigned short* Wh1P = us; us += PKS;
  unsigned short* Wi2P = us; us += PKS;
  unsigned short* Wh2P = us; us += PKS;
  // limb planes: [layer][buf][limb]
  unsigned short* L[3][2][3];
  for (int ly = 0; ly < 3; ++ly)
    for (int bu = 0; bu < 2; ++bu)
      for (int li = 0; li < 3; ++li) { L[ly][bu][li] = us; us += PLN; }
  float* p = (float*)us;
  float* WiT0 = p; p += (size_t)DE * 3 * DH;
  float* G0   = p; p += (size_t)VOC * 3 * DH;
  float* z2hT = p; p += (size_t)DZ * DH;
  float* h2vP = p; p += (size_t)DH * VOC;
  float* H3f  = p; p += (size_t)NROWS * DH;
  int* tokb = (int*)p;
  int* eosb = tokb + NROWS;

  // one-time prep
  {
    int nblk = (int)(PKS / 256);
    pack_w3<<<nblk, 256, 0, stream>>>(W_hh0, Wh0P);
    pack_w3<<<nblk, 256, 0, stream>>>(W_ih1, Wi1P);
    pack_w3<<<nblk, 256, 0, stream>>>(W_hh1, Wh1P);
    pack_w3<<<nblk, 256, 0, stream>>>(W_ih2, Wi2P);
    pack_w3<<<nblk, 256, 0, stream>>>(W_hh2, Wh2P);
  }
  transpose_k<<<dim3(DE / 32, (3 * DH) / 32), dim3(32, 8), 0, stream>>>(
      W_ih0, WiT0, 3 * DH, DE);
  transpose_k<<<dim3(DZ / 32, DH / 32), dim3(32, 8), 0, stream>>>(
      z2h_w, z2hT, DH, DZ);
  repack_k<<<dim3(VOC, DH / 128), 128, 0, stream>>>(h2v_w, h2vP, VOC, DH);
  build_g0<<<dim3(VOC, (3 * DH) / 256), 256, 0, stream>>>(emb, WiT0, b_ih0, G0);

  init_kernel<<<dim3(NROWS / 4, DH / 64), 256, 0, stream>>>(
      Z, z2hT, z2h_b,
      L[0][0][0], L[0][0][1], L[0][0][2],
      L[1][0][0], L[1][0][1], L[1][0][2],
      L[2][0][0], L[2][0][1], L[2][0][2],
      tokb, eosb, outi);

  const int ggrid = (NROWS / 128) * 32;   // 1024 wgs
  int cur = 0;
  for (int t = 1; t < MAXLEN; ++t) {
    int nxt = cur ^ 1;
    gru_mfma<true><<<ggrid, 256, 0, stream>>>(
        nullptr, nullptr, nullptr,
        L[0][cur][0], L[0][cur][1], L[0][cur][2],
        nullptr, Wh0P, tokb, G0, nullptr, b_hh0,
        L[0][nxt][0], L[0][nxt][1], L[0][nxt][2], nullptr);
    gru_mfma<false><<<ggrid, 256, 0, stream>>>(
        L[0][nxt][0], L[0][nxt][1], L[0][nxt][2],
        L[1][cur][0], L[1][cur][1], L[1][cur][2],
        Wi1P, Wh1P, nullptr, nullptr, b_ih1, b_hh1,
        L[1][nxt][0], L[1][nxt][1], L[1][nxt][2], nullptr);
    gru_mfma<false><<<ggrid, 256, 0, stream>>>(
        L[1][nxt][0], L[1][nxt][1], L[1][nxt][2],
        L[2][cur][0], L[2][cur][1], L[2][cur][2],
        Wi2P, Wh2P, nullptr, nullptr, b_ih2, b_hh2,
        L[2][nxt][0], L[2][nxt][1], L[2][nxt][2], H3f);
    argmax_kernel<<<dim3(NROWS / 16), 256, 0, stream>>>(
        H3f, h2vP, h2v_b, tokb, eosb, outi, t);
    cur = nxt;
  }
}

// Round 8
// 37091.299 us; speedup vs baseline: 2.1842x; 1.1976x over previous
//
#include <hip/hip_runtime.h>
#include <math.h>

#define NROWS 4096
#define DZ    128
#define DH    512
#define VOC   64
#define DE    128
#define MAXLEN 128
#define PAD_T 0
#define SOS_T 1
#define EOS_T 2

typedef __attribute__((ext_vector_type(8))) short bf16x8;   // 8 bf16 (4 VGPRs)
typedef __attribute__((ext_vector_type(4))) float f32x4;

__device__ __forceinline__ unsigned short f2bf(float x) {   // RN-even fp32->bf16
  unsigned u = __float_as_uint(x);
  unsigned r = (u + 0x7FFFu + ((u >> 16) & 1u)) >> 16;
  return (unsigned short)r;
}
__device__ __forceinline__ float bf2f(unsigned short b) {
  return __uint_as_float(((unsigned)b) << 16);
}
__device__ __forceinline__ f32x4 mfma_bf16(bf16x8 a, bf16x8 b, f32x4 c) {
  return __builtin_amdgcn_mfma_f32_16x16x32_bf16(a, b, c, 0, 0, 0);
}
#define GLD16(gp, lp)                                                        \
  __builtin_amdgcn_global_load_lds(                                          \
      (const __attribute__((address_space(1))) unsigned int*)(gp),           \
      (__attribute__((address_space(3))) unsigned int*)(lp), 16, 0, 0)

// ---------------- transpose: in [R][C] -> out [C][R] ----------------
__global__ void transpose_k(const float* __restrict__ in, float* __restrict__ out,
                            int R, int C) {
  __shared__ float tile[32][33];
  int cb = blockIdx.x * 32, rb = blockIdx.y * 32;
  int tx = threadIdx.x, ty = threadIdx.y;  // blockDim (32,8)
  #pragma unroll
  for (int i = ty; i < 32; i += 8)
    tile[i][tx] = in[(size_t)(rb + i) * C + (cb + tx)];
  __syncthreads();
  #pragma unroll
  for (int i = ty; i < 32; i += 8)
    out[(size_t)(cb + i) * R + (rb + tx)] = tile[tx][i];
}

// ---------------- repack h2v: in [Rn][K] -> P[((k>>2)*Rn + r)*4 + (k&3)] -----
__global__ void repack_k(const float* __restrict__ in, float* __restrict__ out,
                         int Rn, int K) {
  int k = blockIdx.y * 128 + threadIdx.x;
  int r = blockIdx.x;
  out[((size_t)(k >> 2) * Rn + r) * 4 + (k & 3)] = in[(size_t)r * K + k];
}

// ---- pack weights to 3-limb bf16 B-fragments -------------------------------
// W [3*DH][512] fp32 -> out[g][l][nt][kc][lane][j] bf16
// value = limb_l( W[g*DH + nt*16 + (lane&15)][kc*32 + (lane>>4)*8 + j] )
__global__ void pack_w3(const float* __restrict__ W, unsigned short* __restrict__ out) {
  size_t i = (size_t)blockIdx.x * 256 + threadIdx.x;  // total 9*32*16*512
  int j = (int)(i & 7);
  int lane = (int)((i >> 3) & 63);
  size_t t = i >> 9;
  int kc = (int)(t & 15); t >>= 4;
  int nt = (int)(t & 31); t >>= 5;
  int l = (int)(t % 3);
  int g = (int)(t / 3);
  int n = nt * 16 + (lane & 15);
  int k = kc * 32 + (lane >> 4) * 8 + j;
  float w = W[(size_t)(g * DH + n) * DH + k];
  unsigned short wh = f2bf(w); float fh = bf2f(wh);
  unsigned short wm = f2bf(w - fh); float fm = bf2f(wm);
  unsigned short wl = f2bf(w - fh - fm);
  out[i] = (l == 0) ? wh : (l == 1) ? wm : wl;
}

// ---------------- G0[v][jj] = sum_k emb[v][k] * WiT0[k][jj] + bi[jj] ---------
__global__ __launch_bounds__(256) void build_g0(
    const float* __restrict__ emb, const float* __restrict__ WiT0,
    const float* __restrict__ bi, float* __restrict__ G0) {
  int jj = blockIdx.y * 256 + threadIdx.x;   // grid.y = 3*DH/256
  int v = blockIdx.x;                        // grid.x = VOC
  float acc = bi[jj];
  const float* e = emb + (size_t)v * DE;     // wave-uniform -> s_load
  #pragma unroll 4
  for (int k = 0; k < DE; ++k)
    acc = fmaf(e[k], WiT0[(size_t)k * (3 * DH) + jj], acc);
  G0[(size_t)v * (3 * DH) + jj] = acc;
}

// ---------------- init: h0 = Z @ z2h_w^T + b; 3-limb state init --------------
__global__ __launch_bounds__(256) void init_kernel(
    const float* __restrict__ Z, const float* __restrict__ z2hT,
    const float* __restrict__ z2h_b,
    unsigned short* __restrict__ h1H, unsigned short* __restrict__ h1M, unsigned short* __restrict__ h1L,
    unsigned short* __restrict__ h2H, unsigned short* __restrict__ h2M, unsigned short* __restrict__ h2L,
    unsigned short* __restrict__ h3H, unsigned short* __restrict__ h3M, unsigned short* __restrict__ h3L,
    int* __restrict__ tok, int* __restrict__ eos, int* __restrict__ outi) {
  int lane = threadIdx.x & 63;
  int wave = __builtin_amdgcn_readfirstlane((int)(threadIdx.x >> 6));
  int r = blockIdx.x * 4 + wave;          // grid.x = NROWS/4
  int j = blockIdx.y * 64 + lane;         // grid.y = DH/64
  float acc = z2h_b[j];
  const float* zr = Z + (size_t)r * DZ;   // wave-uniform -> s_load
  #pragma unroll 4
  for (int k = 0; k < DZ; ++k)
    acc = fmaf(zr[k], z2hT[(size_t)k * DH + j], acc);
  size_t o = (size_t)r * DH + j;
  unsigned short uh = f2bf(acc); float fh = bf2f(uh);
  unsigned short um = f2bf(acc - fh); float fm = bf2f(um);
  unsigned short ul = f2bf(acc - fh - fm);
  h1H[o] = uh; h1M[o] = um; h1L[o] = ul;
  h2H[o] = uh; h2M[o] = um; h2L[o] = ul;
  h3H[o] = uh; h3M[o] = um; h3L[o] = ul;
  if (blockIdx.y == 0 && lane == 0) {
    tok[r] = SOS_T;
    eos[r] = 0;
    outi[(size_t)r * MAXLEN] = SOS_T;               // X_gen[:,0] = SOS
    outi[(size_t)NROWS * MAXLEN + r] = MAXLEN;      // seq_lens init
  }
}

// ---------------- fused GRU layer via MFMA + LDS-staged B -------------------
// wg = 4 waves sharing one j-tile (ntile); wave tile = 32 rows x 16 j x 3 gates.
// B fragments stream global->LDS (global_load_lds x16), ping-pong 2-kc chunks,
// one barrier per chunk. A limbs per-lane global 16B loads.
template <bool IS_L0>
__global__ __launch_bounds__(256, 4) void gru_mfma(
    const unsigned short* __restrict__ XH, const unsigned short* __restrict__ XM,
    const unsigned short* __restrict__ XL,   // phase-1 A limbs (L1/L2)
    const unsigned short* __restrict__ HH, const unsigned short* __restrict__ HM,
    const unsigned short* __restrict__ HL,   // phase-2 A limbs (h_prev)
    const unsigned short* __restrict__ WiPk, const unsigned short* __restrict__ WhPk,
    const int* __restrict__ tok, const float* __restrict__ G0,
    const float* __restrict__ bi, const float* __restrict__ bh,
    unsigned short* __restrict__ OH, unsigned short* __restrict__ OM,
    unsigned short* __restrict__ OL, float* __restrict__ Hf32) {
  __shared__ __attribute__((aligned(16))) unsigned short ldsB[2][18 * 512]; // 36 KB
  const int tid  = threadIdx.x;
  const int lane = tid & 63;
  const int wave = __builtin_amdgcn_readfirstlane(tid >> 6);
  const int wg = blockIdx.x;
  const int ntile = wg & 31;           // j-tile
  const int rblk = wg >> 5;            // row block
  const int m0 = rblk * 128 + wave * 32;
  const int col = lane & 15, quad = lane >> 4;
  const int jc = ntile * 16 + col;

  f32x4 acc[2][4];                     // [mt][plane: r,z,in,hn]
  #pragma unroll
  for (int mt = 0; mt < 2; ++mt)
    #pragma unroll
    for (int p = 0; p < 4; ++p)
      acc[mt][p] = (f32x4){0.f, 0.f, 0.f, 0.f};

  // stage chunk c (kc = 2c, 2c+1) of Wp into ldsB[buf]; segs split across waves
  auto stage = [&](const unsigned short* Wp, int c, int buf) {
    for (int s = wave; s < 18; s += 4) {
      int kc2 = s / 9, gl = s - 9 * kc2;     // gl = g*3 + l
      const unsigned short* src =
          Wp + (((size_t)gl * 32 + ntile) * 16 + (c * 2 + kc2)) * 512 + lane * 8;
      GLD16(src, &ldsB[buf][(size_t)s * 512]);
    }
  };

  auto phase = [&](const unsigned short* AH, const unsigned short* AM,
                   const unsigned short* AL, const unsigned short* Wp, int nplane) {
    stage(Wp, 0, 0);
    for (int c = 0; c < 8; ++c) {
      __syncthreads();                       // drains staging of chunk c
      if (c + 1 < 8) stage(Wp, c + 1, (c + 1) & 1);
      const unsigned short* S = ldsB[c & 1];
      #pragma unroll
      for (int kc2 = 0; kc2 < 2; ++kc2) {
        int kc = c * 2 + kc2;
        bf16x8 a[2][3];
        #pragma unroll
        for (int mt = 0; mt < 2; ++mt) {
          size_t ao = (size_t)(m0 + mt * 16 + col) * DH + kc * 32 + quad * 8;
          a[mt][0] = *(const bf16x8*)(AH + ao);
          a[mt][1] = *(const bf16x8*)(AM + ao);
          a[mt][2] = *(const bf16x8*)(AL + ao);
        }
        #pragma unroll
        for (int g = 0; g < 3; ++g) {
          const unsigned short* bp = S + (size_t)(kc2 * 9 + g * 3) * 512 + lane * 8;
          bf16x8 b0 = *(const bf16x8*)(bp);             // limb h
          bf16x8 b1 = *(const bf16x8*)(bp + 512);       // limb m
          bf16x8 b2 = *(const bf16x8*)(bp + 1024);      // limb l
          int pl = (g == 2) ? nplane : g;
          #pragma unroll
          for (int mt = 0; mt < 2; ++mt) {
            f32x4 cc = acc[mt][pl];
            cc = mfma_bf16(a[mt][2], b0, cc);   // Al*Wh  (~2^-18)
            cc = mfma_bf16(a[mt][0], b2, cc);   // Ah*Wl
            cc = mfma_bf16(a[mt][1], b1, cc);   // Am*Wm
            cc = mfma_bf16(a[mt][1], b0, cc);   // Am*Wh  (~2^-9)
            cc = mfma_bf16(a[mt][0], b1, cc);   // Ah*Wm
            cc = mfma_bf16(a[mt][0], b0, cc);   // Ah*Wh
            acc[mt][pl] = cc;
          }
        }
      }
    }
    __syncthreads();                           // protect LDS before next phase
  };

  if constexpr (!IS_L0)
    phase(XH, XM, XL, WiPk, 2);
  phase(HH, HM, HL, WhPk, 3);

  float bhr = bh[jc], bhz = bh[DH + jc], bhn = bh[2 * DH + jc];
  float bir = 0.f, biz = 0.f, bin = 0.f;
  if constexpr (!IS_L0) { bir = bi[jc]; biz = bi[DH + jc]; bin = bi[2 * DH + jc]; }

  #pragma unroll
  for (int mt = 0; mt < 2; ++mt) {
    #pragma unroll
    for (int i = 0; i < 4; ++i) {
      int row = m0 + mt * 16 + quad * 4 + i;
      float gr = acc[mt][0][i] + bhr;
      float gz = acc[mt][1][i] + bhz;
      float gin = acc[mt][2][i];
      float ghn = acc[mt][3][i] + bhn;
      if constexpr (IS_L0) {
        const float* g0p = G0 + (size_t)tok[row] * (3 * DH);
        gr += g0p[jc]; gz += g0p[DH + jc]; gin += g0p[2 * DH + jc];
      } else {
        gr += bir; gz += biz; gin += bin;
      }
      float rg = 1.f / (1.f + expf(-gr));
      float zg = 1.f / (1.f + expf(-gz));
      float nn = tanhf(gin + rg * ghn);
      size_t ho = (size_t)row * DH + jc;
      float hp = bf2f(HH[ho]) + bf2f(HM[ho]) + bf2f(HL[ho]);
      float hv = (1.f - zg) * nn + zg * hp;
      unsigned short uh = f2bf(hv); float fh = bf2f(uh);
      unsigned short um = f2bf(hv - fh); float fm = bf2f(um);
      unsigned short ul = f2bf(hv - fh - fm);
      OH[ho] = uh; OM[ho] = um; OL[ho] = ul;
      if (Hf32) Hf32[ho] = hv;
    }
  }
}

// ---------------- logits + argmax + EOS bookkeeping ----------------
__global__ __launch_bounds__(256) void argmax_kernel(
    const float* __restrict__ H3, const float* __restrict__ h2vP,
    const float* __restrict__ h2v_b,
    int* __restrict__ tok, int* __restrict__ eos,
    int* __restrict__ outi, int t) {
  int lane = threadIdx.x & 63;
  int wave = __builtin_amdgcn_readfirstlane((int)(threadIdx.x >> 6));
  int r0 = blockIdx.x * 16 + wave * 4;    // grid.x = NROWS/16
  float acc[4];
  float b = h2v_b[lane];
  #pragma unroll
  for (int i = 0; i < 4; ++i) acc[i] = b;
  const float4* w4 = (const float4*)h2vP;
  const float4* h4[4];
  #pragma unroll
  for (int i = 0; i < 4; ++i)
    h4[i] = (const float4*)(H3 + (size_t)(r0 + i) * DH);
  #pragma unroll 2
  for (int k4 = 0; k4 < DH / 4; ++k4) {
    float4 w = w4[(size_t)k4 * VOC + lane];       // coalesced vector
    #pragma unroll
    for (int i = 0; i < 4; ++i) {
      float4 h = h4[i][k4];                        // wave-uniform -> s_load
      acc[i] = fmaf(h.x, w.x, acc[i]); acc[i] = fmaf(h.y, w.y, acc[i]);
      acc[i] = fmaf(h.z, w.z, acc[i]); acc[i] = fmaf(h.w, w.w, acc[i]);
    }
  }
  #pragma unroll
  for (int i = 0; i < 4; ++i) {
    float v = acc[i]; int idx = lane;
    #pragma unroll
    for (int off = 32; off >= 1; off >>= 1) {
      float v2 = __shfl_xor(v, off);
      int   i2 = __shfl_xor(idx, off);
      if (v2 > v || (v2 == v && i2 < idx)) { v = v2; idx = i2; }
    }
    if (lane == 0) {
      int r = r0 + i;
      int e = eos[r];
      int x_next = idx;
      outi[(size_t)r * MAXLEN + t] = e ? PAD_T : x_next;
      if (!e && x_next == EOS_T) {
        outi[(size_t)NROWS * MAXLEN + r] = t + 1;  // seq_lens
        eos[r] = 1;
      }
      tok[r] = x_next;
    }
  }
}

// ---------------- host-side orchestration ----------------
extern "C" void kernel_launch(void* const* d_in, const int* in_sizes, int n_in,
                              void* d_out, int out_size, void* d_ws, size_t ws_size,
                              hipStream_t stream) {
  const float* Z      = (const float*)d_in[0];
  const float* emb    = (const float*)d_in[1];
  const float* z2h_w  = (const float*)d_in[2];
  const float* z2h_b  = (const float*)d_in[3];
  const float* W_ih0  = (const float*)d_in[4];
  const float* W_hh0  = (const float*)d_in[5];
  const float* b_ih0  = (const float*)d_in[6];
  const float* b_hh0  = (const float*)d_in[7];
  const float* W_ih1  = (const float*)d_in[8];
  const float* W_hh1  = (const float*)d_in[9];
  const float* b_ih1  = (const float*)d_in[10];
  const float* b_hh1  = (const float*)d_in[11];
  const float* W_ih2  = (const float*)d_in[12];
  const float* W_hh2  = (const float*)d_in[13];
  const float* b_ih2  = (const float*)d_in[14];
  const float* b_hh2  = (const float*)d_in[15];
  const float* h2v_w  = (const float*)d_in[16];
  const float* h2v_b  = (const float*)d_in[17];
  int* outi = (int*)d_out;

  const size_t PKS = (size_t)9 * 32 * 16 * 512;   // ushorts per packed matrix
  const size_t PLN = (size_t)NROWS * DH;          // ushorts per limb plane

  unsigned short* us = (unsigned short*)d_ws;
  unsigned short* Wh0P = us; us += PKS;
  unsigned short* Wi1P = us; us += PKS;
  unsigned short* Wh1P = us; us += PKS;
  unsigned short* Wi2P = us; us += PKS;
  unsigned short* Wh2P = us; us += PKS;
  // limb planes: [layer][buf][limb]
  unsigned short* L[3][2][3];
  for (int ly = 0; ly < 3; ++ly)
    for (int bu = 0; bu < 2; ++bu)
      for (int li = 0; li < 3; ++li) { L[ly][bu][li] = us; us += PLN; }
  float* p = (float*)us;
  float* WiT0 = p; p += (size_t)DE * 3 * DH;
  float* G0   = p; p += (size_t)VOC * 3 * DH;
  float* z2hT = p; p += (size_t)DZ * DH;
  float* h2vP = p; p += (size_t)DH * VOC;
  float* H3f  = p; p += (size_t)NROWS * DH;
  int* tokb = (int*)p;
  int* eosb = tokb + NROWS;

  // one-time prep
  {
    int nblk = (int)(PKS / 256);
    pack_w3<<<nblk, 256, 0, stream>>>(W_hh0, Wh0P);
    pack_w3<<<nblk, 256, 0, stream>>>(W_ih1, Wi1P);
    pack_w3<<<nblk, 256, 0, stream>>>(W_hh1, Wh1P);
    pack_w3<<<nblk, 256, 0, stream>>>(W_ih2, Wi2P);
    pack_w3<<<nblk, 256, 0, stream>>>(W_hh2, Wh2P);
  }
  transpose_k<<<dim3(DE / 32, (3 * DH) / 32), dim3(32, 8), 0, stream>>>(
      W_ih0, WiT0, 3 * DH, DE);
  transpose_k<<<dim3(DZ / 32, DH / 32), dim3(32, 8), 0, stream>>>(
      z2h_w, z2hT, DH, DZ);
  repack_k<<<dim3(VOC, DH / 128), 128, 0, stream>>>(h2v_w, h2vP, VOC, DH);
  build_g0<<<dim3(VOC, (3 * DH) / 256), 256, 0, stream>>>(emb, WiT0, b_ih0, G0);

  init_kernel<<<dim3(NROWS / 4, DH / 64), 256, 0, stream>>>(
      Z, z2hT, z2h_b,
      L[0][0][0], L[0][0][1], L[0][0][2],
      L[1][0][0], L[1][0][1], L[1][0][2],
      L[2][0][0], L[2][0][1], L[2][0][2],
      tokb, eosb, outi);

  const int ggrid = (NROWS / 128) * 32;   // 1024 wgs
  int cur = 0;
  for (int t = 1; t < MAXLEN; ++t) {
    int nxt = cur ^ 1;
    gru_mfma<true><<<ggrid, 256, 0, stream>>>(
        nullptr, nullptr, nullptr,
        L[0][cur][0], L[0][cur][1], L[0][cur][2],
        nullptr, Wh0P, tokb, G0, nullptr, b_hh0,
        L[0][nxt][0], L[0][nxt][1], L[0][nxt][2], nullptr);
    gru_mfma<false><<<ggrid, 256, 0, stream>>>(
        L[0][nxt][0], L[0][nxt][1], L[0][nxt][2],
        L[1][cur][0], L[1][cur][1], L[1][cur][2],
        Wi1P, Wh1P, nullptr, nullptr, b_ih1, b_hh1,
        L[1][nxt][0], L[1][nxt][1], L[1][nxt][2], nullptr);
    gru_mfma<false><<<ggrid, 256, 0, stream>>>(
        L[1][nxt][0], L[1][nxt][1], L[1][nxt][2],
        L[2][cur][0], L[2][cur][1], L[2][cur][2],
        Wi2P, Wh2P, nullptr, nullptr, b_ih2, b_hh2,
        L[2][nxt][0], L[2][nxt][1], L[2][nxt][2], H3f);
    argmax_kernel<<<dim3(NROWS / 16), 256, 0, stream>>>(
        H3f, h2vP, h2v_b, tokb, eosb, outi, t);
    cur = nxt;
  }
}

// Round 9
// 27428.308 us; speedup vs baseline: 2.9537x; 1.3523x over previous
//
#include <hip/hip_runtime.h>
#include <math.h>

#define NROWS 4096
#define DZ    128
#define DH    512
#define VOC   64
#define DE    128
#define MAXLEN 128
#define PAD_T 0
#define SOS_T 1
#define EOS_T 2

typedef __attribute__((ext_vector_type(8))) _Float16 f16x8;  // 8 f16 (4 VGPRs)
typedef __attribute__((ext_vector_type(4))) float f32x4;

__device__ __forceinline__ unsigned short hbits(_Float16 h) {
  return __builtin_bit_cast(unsigned short, h);
}
__device__ __forceinline__ f32x4 mfma_f16(f16x8 a, f16x8 b, f32x4 c) {
  return __builtin_amdgcn_mfma_f32_16x16x32_f16(a, b, c, 0, 0, 0);
}
#define GLD16(gp, lp)                                                        \
  __builtin_amdgcn_global_load_lds(                                          \
      (const __attribute__((address_space(1))) unsigned int*)(gp),           \
      (__attribute__((address_space(3))) unsigned int*)(lp), 16, 0, 0)

// ---------------- transpose: in [R][C] -> out [C][R] ----------------
__global__ void transpose_k(const float* __restrict__ in, float* __restrict__ out,
                            int R, int C) {
  __shared__ float tile[32][33];
  int cb = blockIdx.x * 32, rb = blockIdx.y * 32;
  int tx = threadIdx.x, ty = threadIdx.y;  // blockDim (32,8)
  #pragma unroll
  for (int i = ty; i < 32; i += 8)
    tile[i][tx] = in[(size_t)(rb + i) * C + (cb + tx)];
  __syncthreads();
  #pragma unroll
  for (int i = ty; i < 32; i += 8)
    out[(size_t)(cb + i) * R + (rb + tx)] = tile[tx][i];
}

// ---------------- repack h2v: in [Rn][K] -> P[((k>>2)*Rn + r)*4 + (k&3)] -----
__global__ void repack_k(const float* __restrict__ in, float* __restrict__ out,
                         int Rn, int K) {
  int k = blockIdx.y * 128 + threadIdx.x;
  int r = blockIdx.x;
  out[((size_t)(k >> 2) * Rn + r) * 4 + (k & 3)] = in[(size_t)r * K + k];
}

// ---- pack weights to 2-limb fp16 B-fragments (m-limb scaled by 2^11) -------
// W [3*DH][512] fp32 -> out[g][l][nt][kc][lane][j] f16
// value: limb_l of W[g*DH + nt*16 + (lane&15)][kc*32 + (lane>>4)*8 + j]
__global__ void pack_w2(const float* __restrict__ W, unsigned short* __restrict__ out) {
  size_t i = (size_t)blockIdx.x * 256 + threadIdx.x;  // total 6*32*16*512
  int j = (int)(i & 7);
  int lane = (int)((i >> 3) & 63);
  size_t t = i >> 9;
  int kc = (int)(t & 15); t >>= 4;
  int nt = (int)(t & 31); t >>= 5;
  int l = (int)(t & 1);
  int g = (int)(t >> 1);
  int n = nt * 16 + (lane & 15);
  int k = kc * 32 + (lane >> 4) * 8 + j;
  float w = W[(size_t)(g * DH + n) * DH + k];
  _Float16 wh = (_Float16)w;
  float fh = (float)wh;
  _Float16 wm = (_Float16)((w - fh) * 2048.0f);
  out[i] = hbits(l == 0 ? wh : wm);
}

// ---------------- G0[v][jj] = sum_k emb[v][k] * WiT0[k][jj] + bi[jj] ---------
__global__ __launch_bounds__(256) void build_g0(
    const float* __restrict__ emb, const float* __restrict__ WiT0,
    const float* __restrict__ bi, float* __restrict__ G0) {
  int jj = blockIdx.y * 256 + threadIdx.x;   // grid.y = 3*DH/256
  int v = blockIdx.x;                        // grid.x = VOC
  float acc = bi[jj];
  const float* e = emb + (size_t)v * DE;     // wave-uniform -> s_load
  #pragma unroll 4
  for (int k = 0; k < DE; ++k)
    acc = fmaf(e[k], WiT0[(size_t)k * (3 * DH) + jj], acc);
  G0[(size_t)v * (3 * DH) + jj] = acc;
}

// ---------------- init: h0 = Z @ z2h_w^T + b; 2-limb + f32 state init --------
__global__ __launch_bounds__(256) void init_kernel(
    const float* __restrict__ Z, const float* __restrict__ z2hT,
    const float* __restrict__ z2h_b,
    unsigned short* __restrict__ h1H, unsigned short* __restrict__ h1M, float* __restrict__ f1,
    unsigned short* __restrict__ h2H, unsigned short* __restrict__ h2M, float* __restrict__ f2,
    unsigned short* __restrict__ h3H, unsigned short* __restrict__ h3M, float* __restrict__ f3,
    int* __restrict__ tok, int* __restrict__ eos, int* __restrict__ outi) {
  int lane = threadIdx.x & 63;
  int wave = __builtin_amdgcn_readfirstlane((int)(threadIdx.x >> 6));
  int r = blockIdx.x * 4 + wave;          // grid.x = NROWS/4
  int j = blockIdx.y * 64 + lane;         // grid.y = DH/64
  float acc = z2h_b[j];
  const float* zr = Z + (size_t)r * DZ;   // wave-uniform -> s_load
  #pragma unroll 4
  for (int k = 0; k < DZ; ++k)
    acc = fmaf(zr[k], z2hT[(size_t)k * DH + j], acc);
  size_t o = (size_t)r * DH + j;
  _Float16 uh = (_Float16)acc;
  float fh = (float)uh;
  _Float16 um = (_Float16)((acc - fh) * 2048.0f);
  unsigned short bh_ = hbits(uh), bm_ = hbits(um);
  h1H[o] = bh_; h1M[o] = bm_; f1[o] = acc;
  h2H[o] = bh_; h2M[o] = bm_; f2[o] = acc;
  h3H[o] = bh_; h3M[o] = bm_; f3[o] = acc;
  if (blockIdx.y == 0 && lane == 0) {
    tok[r] = SOS_T;
    eos[r] = 0;
    outi[(size_t)r * MAXLEN] = SOS_T;               // X_gen[:,0] = SOS
    outi[(size_t)NROWS * MAXLEN + r] = MAXLEN;      // seq_lens init
  }
}

// ---------------- fused GRU layer: fp16 2-limb MFMA + LDS-staged B ----------
// wg = 4 waves sharing one j-tile; wave tile = 32 rows x 16 j x 3 gates.
// Products: accH += ah*wh ; accC += am*wh + ah*wm ; gate = accH + accC/2048.
template <bool IS_L0>
__global__ __launch_bounds__(256, 4) void gru_mfma(
    const unsigned short* __restrict__ XH, const unsigned short* __restrict__ XM,
    const unsigned short* __restrict__ HH, const unsigned short* __restrict__ HM,
    const float* __restrict__ Fin,           // prev h fp32 (blend)
    const unsigned short* __restrict__ WiPk, const unsigned short* __restrict__ WhPk,
    const int* __restrict__ tok, const float* __restrict__ G0,
    const float* __restrict__ bi, const float* __restrict__ bh,
    unsigned short* __restrict__ OH, unsigned short* __restrict__ OM,
    float* __restrict__ Fout) {
  __shared__ __attribute__((aligned(16))) unsigned short ldsB[2][12 * 512]; // 24 KB
  const int tid  = threadIdx.x;
  const int lane = tid & 63;
  const int wave = __builtin_amdgcn_readfirstlane(tid >> 6);
  const int wg = blockIdx.x;
  const int ntile = wg & 31;           // j-tile
  const int rblk = wg >> 5;            // row block
  const int m0 = rblk * 128 + wave * 32;
  const int col = lane & 15, quad = lane >> 4;
  const int jc = ntile * 16 + col;

  f32x4 accH[2][4], accC[2][4];        // [mt][plane: r,z,in,hn]
  #pragma unroll
  for (int mt = 0; mt < 2; ++mt)
    #pragma unroll
    for (int p = 0; p < 4; ++p) {
      accH[mt][p] = (f32x4){0.f, 0.f, 0.f, 0.f};
      accC[mt][p] = (f32x4){0.f, 0.f, 0.f, 0.f};
    }

  // stage chunk c (kc = 2c, 2c+1): 12 segs (kc2*6 + g*2 + l), split over waves
  auto stage = [&](const unsigned short* Wp, int c, int buf) {
    for (int s = wave; s < 12; s += 4) {
      int kc2 = s / 6, gl = s - 6 * kc2;
      const unsigned short* src =
          Wp + (((size_t)gl * 32 + ntile) * 16 + (c * 2 + kc2)) * 512 + lane * 8;
      GLD16(src, &ldsB[buf][(size_t)s * 512]);
    }
  };

  auto phase = [&](const unsigned short* AH, const unsigned short* AM,
                   const unsigned short* Wp, int nplane) {
    stage(Wp, 0, 0);
    for (int c = 0; c < 8; ++c) {
      __syncthreads();                       // drains staging of chunk c
      if (c + 1 < 8) stage(Wp, c + 1, (c + 1) & 1);
      const unsigned short* S = ldsB[c & 1];
      #pragma unroll
      for (int kc2 = 0; kc2 < 2; ++kc2) {
        int kc = c * 2 + kc2;
        f16x8 a0[2], a1[2];
        #pragma unroll
        for (int mt = 0; mt < 2; ++mt) {
          size_t ao = (size_t)(m0 + mt * 16 + col) * DH + kc * 32 + quad * 8;
          a0[mt] = *(const f16x8*)(AH + ao);
          a1[mt] = *(const f16x8*)(AM + ao);
        }
        #pragma unroll
        for (int g = 0; g < 3; ++g) {
          const unsigned short* bp = S + (size_t)(kc2 * 6 + g * 2) * 512 + lane * 8;
          f16x8 b0 = *(const f16x8*)(bp);            // limb h
          f16x8 b1 = *(const f16x8*)(bp + 512);      // limb m (x2048)
          int pl = (g == 2) ? nplane : g;
          #pragma unroll
          for (int mt = 0; mt < 2; ++mt) {
            accC[mt][pl] = mfma_f16(a1[mt], b0, accC[mt][pl]);  // am*wh
            accC[mt][pl] = mfma_f16(a0[mt], b1, accC[mt][pl]);  // ah*wm
            accH[mt][pl] = mfma_f16(a0[mt], b0, accH[mt][pl]);  // ah*wh
          }
        }
      }
    }
    __syncthreads();                           // protect LDS before next phase
  };

  if constexpr (!IS_L0)
    phase(XH, XM, WiPk, 2);
  phase(HH, HM, WhPk, 3);

  float bhr = bh[jc], bhz = bh[DH + jc], bhn = bh[2 * DH + jc];
  float bir = 0.f, biz = 0.f, bin = 0.f;
  if constexpr (!IS_L0) { bir = bi[jc]; biz = bi[DH + jc]; bin = bi[2 * DH + jc]; }
  const float IS = 1.0f / 2048.0f;

  #pragma unroll
  for (int mt = 0; mt < 2; ++mt) {
    #pragma unroll
    for (int i = 0; i < 4; ++i) {
      int row = m0 + mt * 16 + quad * 4 + i;
      float gr = accH[mt][0][i] + IS * accC[mt][0][i] + bhr;
      float gz = accH[mt][1][i] + IS * accC[mt][1][i] + bhz;
      float gin = accH[mt][2][i] + IS * accC[mt][2][i];
      float ghn = accH[mt][3][i] + IS * accC[mt][3][i] + bhn;
      if constexpr (IS_L0) {
        const float* g0p = G0 + (size_t)tok[row] * (3 * DH);
        gr += g0p[jc]; gz += g0p[DH + jc]; gin += g0p[2 * DH + jc];
      } else {
        gr += bir; gz += biz; gin += bin;
      }
      float rg = 1.f / (1.f + expf(-gr));
      float zg = 1.f / (1.f + expf(-gz));
      float nn = tanhf(gin + rg * ghn);
      size_t ho = (size_t)row * DH + jc;
      float hp = Fin[ho];                       // exact fp32 prev state
      float hv = (1.f - zg) * nn + zg * hp;
      _Float16 uh = (_Float16)hv;
      float fh = (float)uh;
      _Float16 um = (_Float16)((hv - fh) * 2048.0f);
      OH[ho] = hbits(uh); OM[ho] = hbits(um);
      Fout[ho] = hv;
    }
  }
}

// ---------------- logits + argmax + EOS bookkeeping ----------------
__global__ __launch_bounds__(256) void argmax_kernel(
    const float* __restrict__ H3, const float* __restrict__ h2vP,
    const float* __restrict__ h2v_b,
    int* __restrict__ tok, int* __restrict__ eos,
    int* __restrict__ outi, int t) {
  int lane = threadIdx.x & 63;
  int wave = __builtin_amdgcn_readfirstlane((int)(threadIdx.x >> 6));
  int r0 = blockIdx.x * 16 + wave * 4;    // grid.x = NROWS/16
  float acc[4];
  float b = h2v_b[lane];
  #pragma unroll
  for (int i = 0; i < 4; ++i) acc[i] = b;
  const float4* w4 = (const float4*)h2vP;
  const float4* h4[4];
  #pragma unroll
  for (int i = 0; i < 4; ++i)
    h4[i] = (const float4*)(H3 + (size_t)(r0 + i) * DH);
  #pragma unroll 2
  for (int k4 = 0; k4 < DH / 4; ++k4) {
    float4 w = w4[(size_t)k4 * VOC + lane];       // coalesced vector
    #pragma unroll
    for (int i = 0; i < 4; ++i) {
      float4 h = h4[i][k4];                        // wave-uniform -> s_load
      acc[i] = fmaf(h.x, w.x, acc[i]); acc[i] = fmaf(h.y, w.y, acc[i]);
      acc[i] = fmaf(h.z, w.z, acc[i]); acc[i] = fmaf(h.w, w.w, acc[i]);
    }
  }
  #pragma unroll
  for (int i = 0; i < 4; ++i) {
    float v = acc[i]; int idx = lane;
    #pragma unroll
    for (int off = 32; off >= 1; off >>= 1) {
      float v2 = __shfl_xor(v, off);
      int   i2 = __shfl_xor(idx, off);
      if (v2 > v || (v2 == v && i2 < idx)) { v = v2; idx = i2; }
    }
    if (lane == 0) {
      int r = r0 + i;
      int e = eos[r];
      int x_next = idx;
      outi[(size_t)r * MAXLEN + t] = e ? PAD_T : x_next;
      if (!e && x_next == EOS_T) {
        outi[(size_t)NROWS * MAXLEN + r] = t + 1;  // seq_lens
        eos[r] = 1;
      }
      tok[r] = x_next;
    }
  }
}

// ---------------- host-side orchestration ----------------
extern "C" void kernel_launch(void* const* d_in, const int* in_sizes, int n_in,
                              void* d_out, int out_size, void* d_ws, size_t ws_size,
                              hipStream_t stream) {
  const float* Z      = (const float*)d_in[0];
  const float* emb    = (const float*)d_in[1];
  const float* z2h_w  = (const float*)d_in[2];
  const float* z2h_b  = (const float*)d_in[3];
  const float* W_ih0  = (const float*)d_in[4];
  const float* W_hh0  = (const float*)d_in[5];
  const float* b_ih0  = (const float*)d_in[6];
  const float* b_hh0  = (const float*)d_in[7];
  const float* W_ih1  = (const float*)d_in[8];
  const float* W_hh1  = (const float*)d_in[9];
  const float* b_ih1  = (const float*)d_in[10];
  const float* b_hh1  = (const float*)d_in[11];
  const float* W_ih2  = (const float*)d_in[12];
  const float* W_hh2  = (const float*)d_in[13];
  const float* b_ih2  = (const float*)d_in[14];
  const float* b_hh2  = (const float*)d_in[15];
  const float* h2v_w  = (const float*)d_in[16];
  const float* h2v_b  = (const float*)d_in[17];
  int* outi = (int*)d_out;

  const size_t PKS = (size_t)6 * 32 * 16 * 512;   // ushorts per packed matrix
  const size_t PLN = (size_t)NROWS * DH;          // elems per state plane

  unsigned short* us = (unsigned short*)d_ws;
  unsigned short* Wh0P = us; us += PKS;
  unsigned short* Wi1P = us; us += PKS;
  unsigned short* Wh1P = us; us += PKS;
  unsigned short* Wi2P = us; us += PKS;
  unsigned short* Wh2P = us; us += PKS;
  // fp16 limb planes: [layer][buf][limb]
  unsigned short* L[3][2][2];
  for (int ly = 0; ly < 3; ++ly)
    for (int bu = 0; bu < 2; ++bu)
      for (int li = 0; li < 2; ++li) { L[ly][bu][li] = us; us += PLN; }
  float* p = (float*)us;
  // fp32 state planes: [layer][buf]
  float* F[3][2];
  for (int ly = 0; ly < 3; ++ly)
    for (int bu = 0; bu < 2; ++bu) { F[ly][bu] = p; p += PLN; }
  float* WiT0 = p; p += (size_t)DE * 3 * DH;
  float* G0   = p; p += (size_t)VOC * 3 * DH;
  float* z2hT = p; p += (size_t)DZ * DH;
  float* h2vP = p; p += (size_t)DH * VOC;
  int* tokb = (int*)p;
  int* eosb = tokb + NROWS;

  // one-time prep
  {
    int nblk = (int)(PKS / 256);
    pack_w2<<<nblk, 256, 0, stream>>>(W_hh0, Wh0P);
    pack_w2<<<nblk, 256, 0, stream>>>(W_ih1, Wi1P);
    pack_w2<<<nblk, 256, 0, stream>>>(W_hh1, Wh1P);
    pack_w2<<<nblk, 256, 0, stream>>>(W_ih2, Wi2P);
    pack_w2<<<nblk, 256, 0, stream>>>(W_hh2, Wh2P);
  }
  transpose_k<<<dim3(DE / 32, (3 * DH) / 32), dim3(32, 8), 0, stream>>>(
      W_ih0, WiT0, 3 * DH, DE);
  transpose_k<<<dim3(DZ / 32, DH / 32), dim3(32, 8), 0, stream>>>(
      z2h_w, z2hT, DH, DZ);
  repack_k<<<dim3(VOC, DH / 128), 128, 0, stream>>>(h2v_w, h2vP, VOC, DH);
  build_g0<<<dim3(VOC, (3 * DH) / 256), 256, 0, stream>>>(emb, WiT0, b_ih0, G0);

  init_kernel<<<dim3(NROWS / 4, DH / 64), 256, 0, stream>>>(
      Z, z2hT, z2h_b,
      L[0][0][0], L[0][0][1], F[0][0],
      L[1][0][0], L[1][0][1], F[1][0],
      L[2][0][0], L[2][0][1], F[2][0],
      tokb, eosb, outi);

  const int ggrid = (NROWS / 128) * 32;   // 1024 wgs
  int cur = 0;
  for (int t = 1; t < MAXLEN; ++t) {
    int nxt = cur ^ 1;
    gru_mfma<true><<<ggrid, 256, 0, stream>>>(
        nullptr, nullptr,
        L[0][cur][0], L[0][cur][1], F[0][cur],
        nullptr, Wh0P, tokb, G0, nullptr, b_hh0,
        L[0][nxt][0], L[0][nxt][1], F[0][nxt]);
    gru_mfma<false><<<ggrid, 256, 0, stream>>>(
        L[0][nxt][0], L[0][nxt][1],
        L[1][cur][0], L[1][cur][1], F[1][cur],
        Wi1P, Wh1P, nullptr, nullptr, b_ih1, b_hh1,
        L[1][nxt][0], L[1][nxt][1], F[1][nxt]);
    gru_mfma<false><<<ggrid, 256, 0, stream>>>(
        L[1][nxt][0], L[1][nxt][1],
        L[2][cur][0], L[2][cur][1], F[2][cur],
        Wi2P, Wh2P, nullptr, nullptr, b_ih2, b_hh2,
        L[2][nxt][0], L[2][nxt][1], F[2][nxt]);
    argmax_kernel<<<dim3(NROWS / 16), 256, 0, stream>>>(
        F[2][nxt], h2vP, h2v_b, tokb, eosb, outi, t);
    cur = nxt;
  }
}